// Round 14
// baseline (42.441 us; speedup 1.0000x reference)
//
#include <hip/hip_runtime.h>

#define MAX_SEQ   2048
#define LAT_SEQ   1024
#define DIM       1024
#define DLAT      5
#define K_CB      4375
#define ZERO_IDX  2187   // (0+3)*625 + (0+2)*125 + (0+2)*25 + (0+2)*5 + (0+2)
#define FILLB     512    // fill blocks (dispatched first)
#define COMPB     2048   // compute blocks

typedef float vf4 __attribute__((ext_vector_type(4)));

__device__ __forceinline__ void nt_store4(float4* p, vf4 v) {
    __builtin_nontemporal_store(v, (vf4*)p);
}

// ---------------------------------------------------------------------------
// Block-specialized single dispatch:
//   blocks [0, FILLB)        : pure zero-fill of the masked half (xout rows
//                              s>=1024, masked ze/zq) — fill-kernel shape,
//                              no loads, no LDS, no barriers.
//   blocks [FILLB, FILLB+COMPB): fused encode->quantize->decode for the
//                              unmasked half; 2 tokens per wave; wencT in LDS.
// Fill blocks lead the dispatch order so they interleave with compute blocks.
__global__ __launch_bounds__(256) void fsq_main(
    const float* __restrict__ x,
    const float* __restrict__ Wenc,   // [1024][5]
    const float* __restrict__ Wdec,   // [5][1024]
    float* __restrict__ xout,         // [32768][1024]
    float* __restrict__ ze,           // [32768][5]
    float* __restrict__ zq)           // [32768][5]
{
    __shared__ float wencT[DLAT * DIM];   // [5][1024] (unused by fill blocks)

    const int tid = threadIdx.x;

    if (blockIdx.x < FILLB) {
        // ---- pure fill: masked xout = 16 batches x 1,048,576 floats
        //      (262,144 float4 each, contiguous), masked ze/zq = 16 x 1280 f4.
        const vf4 z4 = {0.f, 0.f, 0.f, 0.f};
        const int tg = blockIdx.x * 256 + tid;            // 0..131071
        float4* xo4 = (float4*)xout;
        #pragma unroll
        for (int k = 0; k < 32; ++k) {
            const int g   = tg + k * (FILLB * 256);       // 0..4,194,303
            const int b16 = g >> 18;                      // / 262144
            const int off = g & 262143;
            nt_store4(xo4 + (long long)b16 * 524288 + 262144 + off, z4);
        }
        if (tg < 20480) {                                 // ze: 16 x 1280 f4
            const int b16 = tg / 1280;
            const int off = tg - b16 * 1280;
            const long long idx = (long long)b16 * 2560 + 1280 + off;
            nt_store4((float4*)ze + idx, z4);
            nt_store4((float4*)zq + idx, z4);
        }
        return;
    }

    // ---- compute block
    const int wave = tid >> 6;
    const int lane = tid & 63;
    const int u0   = ((blockIdx.x - FILLB) * 4 + wave) * 2;  // unmasked ordinal

    int t[2];  long long row[2];
    #pragma unroll
    for (int p = 0; p < 2; ++p) {
        const int u = u0 + p;
        const int b = u >> 10, s = u & 1023;
        t[p]   = b * MAX_SEQ + s;                         // unmasked token
        row[p] = (long long)t[p] * DIM;
    }

    // issue x loads early (8 float4 in flight)
    float4 v[2][4];
    #pragma unroll
    for (int p = 0; p < 2; ++p)
        #pragma unroll
        for (int q = 0; q < 4; ++q)
            v[p][q] = *(const float4*)(x + row[p] + q * 256 + lane * 4);

    // stage transposed Wenc into LDS (20 KB/block, once)
    #pragma unroll
    for (int m = 0; m < 20; ++m) {                        // WencT[e][d] = Wenc[d][e]
        const int k = tid + 256 * m;
        const int e = k >> 10, d = k & 1023;
        wencT[k] = Wenc[d * DLAT + e];
    }
    __syncthreads();

    // encode: h[p][e] = sum_d x[t_p,d] * Wenc[d,e]
    float acc[2][DLAT] = {};
    #pragma unroll
    for (int q = 0; q < 4; ++q) {
        const int c0 = q * 256 + lane * 4;
        #pragma unroll
        for (int e = 0; e < DLAT; ++e) {
            const float4 w = *(const float4*)(wencT + e * DIM + c0);
            #pragma unroll
            for (int p = 0; p < 2; ++p)
                acc[p][e] += v[p][q].x * w.x + v[p][q].y * w.y
                           + v[p][q].z * w.z + v[p][q].w * w.w;
        }
    }
    #pragma unroll
    for (int p = 0; p < 2; ++p)
        #pragma unroll
        for (int e = 0; e < DLAT; ++e) {
            float a = acc[p][e];
            #pragma unroll
            for (int o = 32; o > 0; o >>= 1) a += __shfl_xor(a, o, 64);
            acc[p][e] = a;
        }

    // quantize: z_q = rint(half * tanh(h))  (rint = half-to-even)
    const float halfv[DLAT] = {3.f, 2.f, 2.f, 2.f, 2.f};
    float zqv[2][DLAT];
    #pragma unroll
    for (int p = 0; p < 2; ++p) {
        #pragma unroll
        for (int e = 0; e < DLAT; ++e)
            zqv[p][e] = rintf(halfv[e] * tanhf(acc[p][e]));
        if (lane < DLAT) {
            ze[t[p] * DLAT + lane] = acc[p][lane];
            zq[t[p] * DLAT + lane] = zqv[p][lane];
        }
    }

    // decode: x_out[t,d] = sum_e z_q[e] * Wdec[e,d]; Wdec from L1/L2
    #pragma unroll
    for (int q = 0; q < 4; ++q) {
        const int c0 = q * 256 + lane * 4;
        float4 w[DLAT];
        #pragma unroll
        for (int e = 0; e < DLAT; ++e)
            w[e] = *(const float4*)(Wdec + e * DIM + c0);
        #pragma unroll
        for (int p = 0; p < 2; ++p) {
            vf4 o = {0.f, 0.f, 0.f, 0.f};
            #pragma unroll
            for (int e = 0; e < DLAT; ++e) {
                o.x += zqv[p][e] * w[e].x; o.y += zqv[p][e] * w[e].y;
                o.z += zqv[p][e] * w[e].z; o.w += zqv[p][e] * w[e].w;
            }
            nt_store4((float4*)(xout + row[p] + c0), o);
        }
    }
}

// ---------------------------------------------------------------------------
// Derive codebook usage directly from zq (L2-resident, written by fsq_main):
// one block marks an LDS bitmap with each unmasked token's index, adds the
// always-used zero code (masked tokens), reduces, writes the 3 scalars.
__global__ __launch_bounds__(1024) void finalize(
    const float* __restrict__ zq, float* __restrict__ scal)
{
    __shared__ unsigned char bm[K_CB];
    __shared__ int sh[16];
    const int tid = threadIdx.x;

    for (int i = tid; i < K_CB; i += 1024) bm[i] = 0;
    __syncthreads();

    for (int u = tid; u < 16384; u += 1024) {
        const int t = (u >> 10) * MAX_SEQ + (u & 1023);
        const float* z = zq + (long long)t * DLAT;
        const int c0 = (int)z[0], c1 = (int)z[1], c2 = (int)z[2],
                  c3 = (int)z[3], c4 = (int)z[4];
        const int idx = ((((c0 + 3) * 5 + (c1 + 2)) * 5 + (c2 + 2)) * 5
                          + (c3 + 2)) * 5 + (c4 + 2);
        bm[idx] = 1;
    }
    __syncthreads();
    if (tid == 0) bm[ZERO_IDX] = 1;      // masked tokens always use zero code
    __syncthreads();

    int sum = 0;
    for (int i = tid; i < K_CB; i += 1024) sum += bm[i];
    #pragma unroll
    for (int o = 32; o > 0; o >>= 1) sum += __shfl_xor(sum, o, 64);
    if ((tid & 63) == 0) sh[tid >> 6] = sum;
    __syncthreads();
    if (tid == 0) {
        int tot = 0;
        #pragma unroll
        for (int wv = 0; wv < 16; ++wv) tot += sh[wv];
        const float uniq  = (float)tot;
        const float usage = (uniq + ((float)K_CB - uniq) * expf(-1.0f)) / (float)K_CB;
        scal[0] = usage;          // output 3: usage
        scal[1] = uniq;           // output 4: unique (stored as its value)
        scal[2] = 0.0f;           // output 5: percent_masked
    }
}

// ---------------------------------------------------------------------------
extern "C" void kernel_launch(void* const* d_in, const int* in_sizes, int n_in,
                              void* d_out, int out_size, void* d_ws, size_t ws_size,
                              hipStream_t stream) {
    const float* x    = (const float*)d_in[0];   // [16,2048,1024]
    const float* Wenc = (const float*)d_in[1];   // [1024,5]
    const float* Wdec = (const float*)d_in[2];   // [5,1024]

    float* out  = (float*)d_out;
    float* xout = out;                                  // 33554432
    float* ze   = out + 33554432;                       // 163840
    float* zq   = ze + 163840;                          // 163840
    float* scal = zq + 163840;                          // 3 scalars

    (void)d_ws; (void)ws_size;                          // workspace unused

    fsq_main<<<FILLB + COMPB, 256, 0, stream>>>(x, Wenc, Wdec, xout, ze, zq);
    finalize<<<1, 1024, 0, stream>>>(zq, scal);
}

// Round 15
// 40.408 us; speedup vs baseline: 1.0503x; 1.0503x over previous
//
#include <hip/hip_runtime.h>

#define MAX_SEQ   2048
#define LAT_SEQ   1024
#define DIM       1024
#define DLAT      5
#define K_CB      4375
#define ZERO_IDX  2187   // (0+3)*625 + (0+2)*125 + (0+2)*25 + (0+2)*5 + (0+2)

typedef float vf4 __attribute__((ext_vector_type(4)));

__device__ __forceinline__ void nt_store4(float* p, vf4 v) {
    __builtin_nontemporal_store(v, (vf4*)p);
}

// ---------------------------------------------------------------------------
// Fused encode -> quantize -> decode. One wave per 2 (unmasked, masked) token
// pairs, 256-thread blocks, grid 2048. wencT staged in LDS (20 KB/block, paid
// once per block — per-wave global Wenc reads are 80B-strided, 5x TA cost;
// measured +16us in R12). Wdec from global/L1. xout via nontemporal stores.
// No used[] bitmap: finalize re-derives codebook indices from zq.
// Measured best configuration: 40.8 us clean (R13).
__global__ __launch_bounds__(256) void fsq_main(
    const float* __restrict__ x,
    const float* __restrict__ Wenc,   // [1024][5]
    const float* __restrict__ Wdec,   // [5][1024]
    float* __restrict__ xout,         // [32768][1024]
    float* __restrict__ ze,           // [32768][5]
    float* __restrict__ zq)           // [32768][5]
{
    __shared__ float wencT[DLAT * DIM];   // [5][1024]

    const int tid  = threadIdx.x;
    const int wave = tid >> 6;
    const int lane = tid & 63;
    const int u0   = (blockIdx.x * 4 + wave) * 2;    // unmasked ordinal base

    int t[2];  long long row[2], rowm[2];
    #pragma unroll
    for (int p = 0; p < 2; ++p) {
        const int u = u0 + p;
        const int b = u >> 10, s = u & 1023;
        t[p]    = b * MAX_SEQ + s;                    // unmasked token
        row[p]  = (long long)t[p] * DIM;
        rowm[p] = row[p] + (long long)LAT_SEQ * DIM;  // masked partner row
    }

    // ---- issue x loads early (8 float4 in flight)
    float4 v[2][4];
    #pragma unroll
    for (int p = 0; p < 2; ++p)
        #pragma unroll
        for (int q = 0; q < 4; ++q)
            v[p][q] = *(const float4*)(x + row[p] + q * 256 + lane * 4);

    // ---- masked partners: independent zero-store work hides load latency
    const vf4 z4 = {0.f, 0.f, 0.f, 0.f};
    #pragma unroll
    for (int p = 0; p < 2; ++p) {
        #pragma unroll
        for (int q = 0; q < 4; ++q)
            nt_store4(xout + rowm[p] + q * 256 + lane * 4, z4);
        if (lane < DLAT) {
            const int tm = t[p] + LAT_SEQ;
            ze[tm * DLAT + lane] = 0.f;
            zq[tm * DLAT + lane] = 0.f;
        }
    }

    // ---- stage transposed Wenc into LDS (20 KB/block, once)
    #pragma unroll
    for (int m = 0; m < 20; ++m) {                    // WencT[e][d] = Wenc[d][e]
        const int k = tid + 256 * m;
        const int e = k >> 10, d = k & 1023;
        wencT[k] = Wenc[d * DLAT + e];
    }
    __syncthreads();

    // ---- encode: h[p][e] = sum_d x[t_p,d] * Wenc[d,e]
    float acc[2][DLAT] = {};
    #pragma unroll
    for (int q = 0; q < 4; ++q) {
        const int c0 = q * 256 + lane * 4;
        #pragma unroll
        for (int e = 0; e < DLAT; ++e) {
            const float4 w = *(const float4*)(wencT + e * DIM + c0);
            #pragma unroll
            for (int p = 0; p < 2; ++p)
                acc[p][e] += v[p][q].x * w.x + v[p][q].y * w.y
                           + v[p][q].z * w.z + v[p][q].w * w.w;
        }
    }
    #pragma unroll
    for (int p = 0; p < 2; ++p)
        #pragma unroll
        for (int e = 0; e < DLAT; ++e) {
            float a = acc[p][e];
            #pragma unroll
            for (int o = 32; o > 0; o >>= 1) a += __shfl_xor(a, o, 64);
            acc[p][e] = a;
        }

    // ---- quantize: z_q = rint(half * tanh(h))  (rint = half-to-even)
    const float halfv[DLAT] = {3.f, 2.f, 2.f, 2.f, 2.f};
    float zqv[2][DLAT];
    #pragma unroll
    for (int p = 0; p < 2; ++p) {
        #pragma unroll
        for (int e = 0; e < DLAT; ++e)
            zqv[p][e] = rintf(halfv[e] * tanhf(acc[p][e]));
        if (lane < DLAT) {
            ze[t[p] * DLAT + lane] = acc[p][lane];
            zq[t[p] * DLAT + lane] = zqv[p][lane];
        }
    }

    // ---- decode: x_out[t,d] = sum_e z_q[e] * Wdec[e,d]; Wdec from L1/L2
    #pragma unroll
    for (int q = 0; q < 4; ++q) {
        const int c0 = q * 256 + lane * 4;
        float4 w[DLAT];
        #pragma unroll
        for (int e = 0; e < DLAT; ++e)
            w[e] = *(const float4*)(Wdec + e * DIM + c0);
        #pragma unroll
        for (int p = 0; p < 2; ++p) {
            vf4 o = {0.f, 0.f, 0.f, 0.f};
            #pragma unroll
            for (int e = 0; e < DLAT; ++e) {
                o.x += zqv[p][e] * w[e].x; o.y += zqv[p][e] * w[e].y;
                o.z += zqv[p][e] * w[e].z; o.w += zqv[p][e] * w[e].w;
            }
            nt_store4(xout + row[p] + c0, o);
        }
    }
}

// ---------------------------------------------------------------------------
// Derive codebook usage directly from zq (L2-resident, written by fsq_main):
// one block marks an LDS bitmap with each unmasked token's index, adds the
// always-used zero code (masked tokens), reduces, writes the 3 scalars.
__global__ __launch_bounds__(1024) void finalize(
    const float* __restrict__ zq, float* __restrict__ scal)
{
    __shared__ unsigned char bm[K_CB];
    __shared__ int sh[16];
    const int tid = threadIdx.x;

    for (int i = tid; i < K_CB; i += 1024) bm[i] = 0;
    __syncthreads();

    for (int u = tid; u < 16384; u += 1024) {
        const int t = (u >> 10) * MAX_SEQ + (u & 1023);
        const float* z = zq + (long long)t * DLAT;
        const int c0 = (int)z[0], c1 = (int)z[1], c2 = (int)z[2],
                  c3 = (int)z[3], c4 = (int)z[4];
        const int idx = ((((c0 + 3) * 5 + (c1 + 2)) * 5 + (c2 + 2)) * 5
                          + (c3 + 2)) * 5 + (c4 + 2);
        bm[idx] = 1;
    }
    __syncthreads();
    if (tid == 0) bm[ZERO_IDX] = 1;      // masked tokens always use zero code
    __syncthreads();

    int sum = 0;
    for (int i = tid; i < K_CB; i += 1024) sum += bm[i];
    #pragma unroll
    for (int o = 32; o > 0; o >>= 1) sum += __shfl_xor(sum, o, 64);
    if ((tid & 63) == 0) sh[tid >> 6] = sum;
    __syncthreads();
    if (tid == 0) {
        int tot = 0;
        #pragma unroll
        for (int wv = 0; wv < 16; ++wv) tot += sh[wv];
        const float uniq  = (float)tot;
        const float usage = (uniq + ((float)K_CB - uniq) * expf(-1.0f)) / (float)K_CB;
        scal[0] = usage;          // output 3: usage
        scal[1] = uniq;           // output 4: unique (stored as its value)
        scal[2] = 0.0f;           // output 5: percent_masked
    }
}

// ---------------------------------------------------------------------------
extern "C" void kernel_launch(void* const* d_in, const int* in_sizes, int n_in,
                              void* d_out, int out_size, void* d_ws, size_t ws_size,
                              hipStream_t stream) {
    const float* x    = (const float*)d_in[0];   // [16,2048,1024]
    const float* Wenc = (const float*)d_in[1];   // [1024,5]
    const float* Wdec = (const float*)d_in[2];   // [5,1024]

    float* out  = (float*)d_out;
    float* xout = out;                                  // 33554432
    float* ze   = out + 33554432;                       // 163840
    float* zq   = ze + 163840;                          // 163840
    float* scal = zq + 163840;                          // 3 scalars

    (void)d_ws; (void)ws_size;                          // workspace unused

    fsq_main<<<2048, 256, 0, stream>>>(x, Wenc, Wdec, xout, ze, zq);
    finalize<<<1, 1024, 0, stream>>>(zq, scal);
}